// Round 1
// baseline (387.933 us; speedup 1.0000x reference)
//
#include <hip/hip_runtime.h>

#define CI    32
#define IH    224
#define IW    224
#define OHS   220
#define OWS   220
#define NF    64
#define KS    5
#define XCOLS 228
#define CP    36                 // c padding for x LDS (b64-friendly, conflict-free)
#define WPD   40                 // c padding for w LDS (b128-friendly, conflict-free)
#define NBUFW (KS * NF * WPD)    // 12800 elems per weight buffer

typedef __attribute__((ext_vector_type(4))) float   f32x4;
typedef __attribute__((ext_vector_type(4))) __bf16  bf16x4;
typedef __attribute__((ext_vector_type(8))) __bf16  bf16x8;

// Repack weights fp32 [f][c][kh][kw] -> bf16 [tap=kh*5+kw][f][c] in d_ws.
__global__ void repack_w_kernel(const float* __restrict__ w, __bf16* __restrict__ wp) {
  int i = blockIdx.x * 256 + threadIdx.x;
  if (i >= KS * KS * NF * CI) return;
  int c   = i & (CI - 1);
  int f   = (i >> 5) & (NF - 1);
  int tap = i >> 11;
  int kh = tap / KS, kw = tap % KS;
  wp[i] = (__bf16)w[((f * CI + c) * KS + kh) * KS + kw];
}

template <bool USE_WS>
__global__ __launch_bounds__(256, 1)
void conv_main(const float* __restrict__ x, const float* __restrict__ w,
               const __bf16* __restrict__ wp, const float* __restrict__ bias,
               float* __restrict__ out) {
  __shared__ __bf16 xs[6 * XCOLS * CP];   // 98496 B
  __shared__ __bf16 wsm[2 * NBUFW];       // 51200 B

  const int tid  = threadIdx.x;
  const int lane = tid & 63;
  const int wv   = tid >> 6;
  const int m    = lane & 15;   // MFMA row (A) / col (B,C)
  const int q    = lane >> 4;   // quad -> k-chunk / C row group

  // XCD-aware swizzle: 8 XCDs, give each a contiguous run of 220 logical blocks
  int bid = blockIdx.x;
  int lid = (bid >> 3) + (bid & 7) * 220;   // bijection on [0,1760)
  const int n   = lid / 110;
  const int oh0 = (lid % 110) * 2;          // output rows oh0, oh0+1

  // ---- stage x rows oh0..oh0+5, cols 0..223, all 32 c, as [row][col][c] bf16 ----
  {
    const float* xn = x + (size_t)n * CI * IH * IW;
    for (int p = tid; p < 2688; p += 256) {     // 4col x 4c patches
      int pc   = p & 7;          // c group (4 c each)
      int pg   = p >> 3;
      int pcol = pg % 56;        // col group (4 cols each)
      int prow = pg / 56;        // 0..5
      int row  = oh0 + prow;
      f32x4 v0 = *(const f32x4*)(xn + ((size_t)(pc * 4 + 0) * IH + row) * IW + pcol * 4);
      f32x4 v1 = *(const f32x4*)(xn + ((size_t)(pc * 4 + 1) * IH + row) * IW + pcol * 4);
      f32x4 v2 = *(const f32x4*)(xn + ((size_t)(pc * 4 + 2) * IH + row) * IW + pcol * 4);
      f32x4 v3 = *(const f32x4*)(xn + ((size_t)(pc * 4 + 3) * IH + row) * IW + pcol * 4);
#pragma unroll
      for (int dcol = 0; dcol < 4; ++dcol) {
        bf16x4 t;
        t[0] = (__bf16)v0[dcol]; t[1] = (__bf16)v1[dcol];
        t[2] = (__bf16)v2[dcol]; t[3] = (__bf16)v3[dcol];
        *(bf16x4*)&xs[(prow * XCOLS + pcol * 4 + dcol) * CP + pc * 4] = t;
      }
    }
    // zero pad columns 224..227 (only feed masked outputs, but avoid NaN surprises)
    for (int z = tid; z < 6 * 4 * CP; z += 256) {
      int rr  = z / (4 * CP);
      int rem = z - rr * (4 * CP);
      xs[(rr * XCOLS + 224) * CP + rem] = (__bf16)0.0f;
    }
  }

  // ---- stage weights for kh=0 into buffer 0: [kw][f][c] ----
  if (USE_WS) {
    for (int i = tid; i < NF * CI * KS / 8; i += 256) {   // 1280 chunks of 8
      int c0 = (i & 3) * 8;
      int f  = (i >> 2) & 63;
      int kw = i >> 8;
      bf16x8 v = *(const bf16x8*)(wp + ((size_t)(0 * KS + kw) * NF + f) * CI + c0);
      *(bf16x8*)&wsm[(kw * NF + f) * WPD + c0] = v;
    }
  } else {
    for (int i = tid; i < KS * NF * CI; i += 256) {       // 10240 scalar gathers
      int c  = i & 31;
      int f  = (i >> 5) & 63;
      int kw = i >> 11;
      wsm[(kw * NF + f) * WPD + c] = (__bf16)w[((f * CI + c) * KS + 0) * KS + kw];
    }
  }
  __syncthreads();

  // per-wave px-tile geometry (tiles t = wv + 4j, j=0..6 over 28 tiles)
  int rj[7], cbj[7], xoff[7];
#pragma unroll
  for (int j = 0; j < 7; ++j) {
    int t   = wv + j * 4;
    rj[j]   = t / 14;
    cbj[j]  = (t % 14) * 16;
    xoff[j] = (rj[j] * XCOLS + cbj[j] + m) * CP + q * 8;
  }

  f32x4 acc[28];
#pragma unroll
  for (int i = 0; i < 28; ++i) { f32x4 z = {0.f, 0.f, 0.f, 0.f}; acc[i] = z; }

  for (int kh = 0; kh < KS; ++kh) {
    const int buf = kh & 1;
    const __bf16* wb = &wsm[buf * NBUFW];

    // prefetch next kh's weights into registers (latency hidden under MFMA)
    bf16x8 pw[5];
    if (USE_WS && kh < KS - 1) {
#pragma unroll
      for (int it = 0; it < 5; ++it) {
        int e  = it * 256 + tid;
        int c0 = (e & 3) * 8;
        int f  = (e >> 2) & 63;
        int kw = e >> 8;
        pw[it] = *(const bf16x8*)(wp + ((size_t)((kh + 1) * KS + kw) * NF + f) * CI + c0);
      }
    }

#pragma unroll
    for (int kw = 0; kw < KS; ++kw) {
      bf16x8 af[4];
#pragma unroll
      for (int ft = 0; ft < 4; ++ft)
        af[ft] = *(const bf16x8*)&wb[(kw * NF + ft * 16 + m) * WPD + q * 8];
#pragma unroll
      for (int j = 0; j < 7; ++j) {
        const __bf16* bp = &xs[xoff[j] + (kh * XCOLS + kw) * CP];
        bf16x4 lo = *(const bf16x4*)bp;
        bf16x4 hi = *(const bf16x4*)(bp + 4);
        bf16x8 bv8 = __builtin_shufflevector(lo, hi, 0, 1, 2, 3, 4, 5, 6, 7);
#pragma unroll
        for (int ft = 0; ft < 4; ++ft)
          acc[j * 4 + ft] =
              __builtin_amdgcn_mfma_f32_16x16x32_bf16(af[ft], bv8, acc[j * 4 + ft], 0, 0, 0);
      }
    }

    if (kh < KS - 1) {
      if (USE_WS) {
#pragma unroll
        for (int it = 0; it < 5; ++it) {
          int e  = it * 256 + tid;
          int c0 = (e & 3) * 8;
          int f  = (e >> 2) & 63;
          int kw = e >> 8;
          *(bf16x8*)&wsm[(buf ^ 1) * NBUFW + (kw * NF + f) * WPD + c0] = pw[it];
        }
      } else {
        for (int i = tid; i < KS * NF * CI; i += 256) {
          int c  = i & 31;
          int f  = (i >> 5) & 63;
          int kw = i >> 11;
          wsm[(buf ^ 1) * NBUFW + (kw * NF + f) * WPD + c] =
              (__bf16)w[((f * CI + c) * KS + (kh + 1)) * KS + kw];
        }
      }
      __syncthreads();
    }
  }

  // ---- epilogue: C/D layout col=lane&15 (pixel), row=q*4+reg (filter within 16) ----
  float bvv[16];
#pragma unroll
  for (int ft = 0; ft < 4; ++ft)
#pragma unroll
    for (int rg = 0; rg < 4; ++rg)
      bvv[ft * 4 + rg] = bias[ft * 16 + q * 4 + rg];

#pragma unroll
  for (int j = 0; j < 7; ++j) {
    int ow = cbj[j] + m;
    if (ow < OWS) {
      int oh = oh0 + rj[j];
#pragma unroll
      for (int ft = 0; ft < 4; ++ft) {
#pragma unroll
        for (int rg = 0; rg < 4; ++rg) {
          int f = ft * 16 + q * 4 + rg;
          out[(((size_t)n * NF + f) * OHS + oh) * OWS + ow] = acc[j * 4 + ft][rg] + bvv[ft * 4 + rg];
        }
      }
    }
  }
}

extern "C" void kernel_launch(void* const* d_in, const int* in_sizes, int n_in,
                              void* d_out, int out_size, void* d_ws, size_t ws_size,
                              hipStream_t stream) {
  const float* x    = (const float*)d_in[0];
  const float* w    = (const float*)d_in[1];
  const float* bias = (const float*)d_in[2];
  float* out = (float*)d_out;

  const int NW = KS * KS * NF * CI;  // 51200 repacked weight elems
  if (ws_size >= (size_t)NW * sizeof(__bf16)) {
    __bf16* wp = (__bf16*)d_ws;
    repack_w_kernel<<<(NW + 255) / 256, 256, 0, stream>>>(w, wp);
    conv_main<true><<<1760, 256, 0, stream>>>(x, w, wp, bias, out);
  } else {
    conv_main<false><<<1760, 256, 0, stream>>>(x, w, nullptr, bias, out);
  }
}

// Round 2
// 374.039 us; speedup vs baseline: 1.0371x; 1.0371x over previous
//
#include <hip/hip_runtime.h>

#define CI    32
#define IH    224
#define IW    224
#define OHS   220
#define OWS   220
#define NF    64
#define KS    5
#define XCOLS 228
#define CP    36                 // c padding for x LDS (conflict-spread, b64 reads)
#define WPD   40                 // c padding for w LDS (b128-friendly)
#define XROWS 8                  // staged input rows per block (4 output rows + 4 halo)
#define NBUFW (KS * NF * WPD)    // 12800 elems, single weight buffer

typedef __attribute__((ext_vector_type(4))) float   f32x4;
typedef __attribute__((ext_vector_type(4))) __bf16  bf16x4;
typedef __attribute__((ext_vector_type(8))) __bf16  bf16x8;

// Repack weights fp32 [f][c][kh][kw] -> bf16 [tap=kh*5+kw][f][c] in d_ws.
__global__ void repack_w_kernel(const float* __restrict__ w, __bf16* __restrict__ wp) {
  int i = blockIdx.x * 256 + threadIdx.x;
  if (i >= KS * KS * NF * CI) return;
  int c   = i & (CI - 1);
  int f   = (i >> 5) & (NF - 1);
  int tap = i >> 11;
  int kh = tap / KS, kw = tap % KS;
  wp[i] = (__bf16)w[((f * CI + c) * KS + kh) * KS + kw];
}

template <bool USE_WS>
__global__ __launch_bounds__(512, 1)
void conv_main(const float* __restrict__ x, const float* __restrict__ w,
               const __bf16* __restrict__ wp, const float* __restrict__ bias,
               float* __restrict__ out) {
  __shared__ __bf16 xs[XROWS * XCOLS * CP];  // 65664 elems = 131328 B
  __shared__ __bf16 wsm[NBUFW];              // 12800 elems = 25600 B  (total 156928 B)

  const int tid  = threadIdx.x;
  const int lane = tid & 63;
  const int wv   = tid >> 6;    // 0..7
  const int m    = lane & 15;   // MFMA row (A) / col (B,C)
  const int q    = lane >> 4;   // quad -> k-chunk / C row group

  // XCD-aware swizzle over 880 = 8 * 110 logical blocks
  int bid = blockIdx.x;
  int lid = (bid >> 3) + (bid & 7) * 110;   // bijection on [0,880)
  const int n   = lid / 55;
  const int oh0 = (lid % 55) * 4;           // output rows oh0..oh0+3 (max 216..219)

  // ---- stage x rows oh0..oh0+7, cols 0..223, all 32 c, as [row][col][c] bf16 ----
  {
    const float* xn = x + (size_t)n * CI * IH * IW;
    for (int p = tid; p < XROWS * 56 * 8; p += 512) {   // 4col x 4c patches
      int pc   = p & 7;          // c group (4 c each)
      int pg   = p >> 3;
      int pcol = pg % 56;        // col group (4 cols each)
      int prow = pg / 56;        // 0..7
      int row  = oh0 + prow;     // <= 223
      f32x4 v0 = *(const f32x4*)(xn + ((size_t)(pc * 4 + 0) * IH + row) * IW + pcol * 4);
      f32x4 v1 = *(const f32x4*)(xn + ((size_t)(pc * 4 + 1) * IH + row) * IW + pcol * 4);
      f32x4 v2 = *(const f32x4*)(xn + ((size_t)(pc * 4 + 2) * IH + row) * IW + pcol * 4);
      f32x4 v3 = *(const f32x4*)(xn + ((size_t)(pc * 4 + 3) * IH + row) * IW + pcol * 4);
#pragma unroll
      for (int dcol = 0; dcol < 4; ++dcol) {
        bf16x4 t;
        t[0] = (__bf16)v0[dcol]; t[1] = (__bf16)v1[dcol];
        t[2] = (__bf16)v2[dcol]; t[3] = (__bf16)v3[dcol];
        *(bf16x4*)&xs[(prow * XCOLS + pcol * 4 + dcol) * CP + pc * 4] = t;
      }
    }
    // zero pad columns 224..227
    for (int z = tid; z < XROWS * 4 * CP; z += 512) {
      int rr  = z / (4 * CP);
      int rem = z - rr * (4 * CP);
      xs[(rr * XCOLS + 224) * CP + rem] = (__bf16)0.0f;
    }
  }

  // ---- stage weights for kh=0: [kw][f][c] ----
  if (USE_WS) {
    for (int i = tid; i < NF * CI * KS / 8; i += 512) {   // 1280 chunks of 8
      int c0 = (i & 3) * 8;
      int f  = (i >> 2) & 63;
      int kw = i >> 8;
      bf16x8 v = *(const bf16x8*)(wp + ((size_t)(0 * KS + kw) * NF + f) * CI + c0);
      *(bf16x8*)&wsm[(kw * NF + f) * WPD + c0] = v;
    }
  } else {
    for (int i = tid; i < KS * NF * CI; i += 512) {
      int c  = i & 31;
      int f  = (i >> 5) & 63;
      int kw = i >> 11;
      wsm[(kw * NF + f) * WPD + c] = (__bf16)w[((f * CI + c) * KS + 0) * KS + kw];
    }
  }
  __syncthreads();

  // per-wave px-tile geometry: tiles t = wv + 8j, j=0..6 over 56 tiles (4 rows x 14)
  int rj[7], cbj[7], xoff[7];
#pragma unroll
  for (int j = 0; j < 7; ++j) {
    int t   = wv + j * 8;
    rj[j]   = t / 14;            // output row offset 0..3
    cbj[j]  = (t % 14) * 16;
    xoff[j] = (rj[j] * XCOLS + cbj[j] + m) * CP + q * 8;
  }

  f32x4 acc[28];
#pragma unroll
  for (int i = 0; i < 28; ++i) { f32x4 z = {0.f, 0.f, 0.f, 0.f}; acc[i] = z; }

  for (int kh = 0; kh < KS; ++kh) {
    // prefetch next kh's weights into registers (hidden under MFMA)
    bf16x8 pw[3];
    if (USE_WS && kh < KS - 1) {
#pragma unroll
      for (int it = 0; it < 3; ++it) {
        int e = it * 512 + tid;
        if (e < 1280) {
          int c0 = (e & 3) * 8;
          int f  = (e >> 2) & 63;
          int kw = e >> 8;
          pw[it] = *(const bf16x8*)(wp + ((size_t)((kh + 1) * KS + kw) * NF + f) * CI + c0);
        }
      }
    }

#pragma unroll
    for (int kw = 0; kw < KS; ++kw) {
      bf16x8 af[4];
#pragma unroll
      for (int ft = 0; ft < 4; ++ft)
        af[ft] = *(const bf16x8*)&wsm[(kw * NF + ft * 16 + m) * WPD + q * 8];
#pragma unroll
      for (int j = 0; j < 7; ++j) {
        const __bf16* bp = &xs[xoff[j] + (kh * XCOLS + kw) * CP];
        bf16x4 lo = *(const bf16x4*)bp;
        bf16x4 hi = *(const bf16x4*)(bp + 4);
        bf16x8 bv8 = __builtin_shufflevector(lo, hi, 0, 1, 2, 3, 4, 5, 6, 7);
#pragma unroll
        for (int ft = 0; ft < 4; ++ft)
          acc[j * 4 + ft] =
              __builtin_amdgcn_mfma_f32_16x16x32_bf16(af[ft], bv8, acc[j * 4 + ft], 0, 0, 0);
      }
    }

    if (kh < KS - 1) {
      __syncthreads();   // all waves done reading wsm for this kh
      if (USE_WS) {
#pragma unroll
        for (int it = 0; it < 3; ++it) {
          int e = it * 512 + tid;
          if (e < 1280) {
            int c0 = (e & 3) * 8;
            int f  = (e >> 2) & 63;
            int kw = e >> 8;
            *(bf16x8*)&wsm[(kw * NF + f) * WPD + c0] = pw[it];
          }
        }
      } else {
        for (int i = tid; i < KS * NF * CI; i += 512) {
          int c  = i & 31;
          int f  = (i >> 5) & 63;
          int kw = i >> 11;
          wsm[(kw * NF + f) * WPD + c] =
              (__bf16)w[((f * CI + c) * KS + (kh + 1)) * KS + kw];
        }
      }
      __syncthreads();
    }
  }

  // ---- epilogue: C/D layout col=lane&15 (pixel), row=q*4+reg (filter within 16) ----
  float bvv[16];
#pragma unroll
  for (int ft = 0; ft < 4; ++ft)
#pragma unroll
    for (int rg = 0; rg < 4; ++rg)
      bvv[ft * 4 + rg] = bias[ft * 16 + q * 4 + rg];

#pragma unroll
  for (int j = 0; j < 7; ++j) {
    int ow = cbj[j] + m;
    if (ow < OWS) {
      int oh = oh0 + rj[j];
#pragma unroll
      for (int ft = 0; ft < 4; ++ft) {
#pragma unroll
        for (int rg = 0; rg < 4; ++rg) {
          int f = ft * 16 + q * 4 + rg;
          out[(((size_t)n * NF + f) * OHS + oh) * OWS + ow] = acc[j * 4 + ft][rg] + bvv[ft * 4 + rg];
        }
      }
    }
  }
}

extern "C" void kernel_launch(void* const* d_in, const int* in_sizes, int n_in,
                              void* d_out, int out_size, void* d_ws, size_t ws_size,
                              hipStream_t stream) {
  const float* x    = (const float*)d_in[0];
  const float* w    = (const float*)d_in[1];
  const float* bias = (const float*)d_in[2];
  float* out = (float*)d_out;

  const int NW = KS * KS * NF * CI;  // 51200 repacked weight elems
  if (ws_size >= (size_t)NW * sizeof(__bf16)) {
    __bf16* wp = (__bf16*)d_ws;
    repack_w_kernel<<<(NW + 255) / 256, 256, 0, stream>>>(w, wp);
    conv_main<true><<<880, 512, 0, stream>>>(x, w, wp, bias, out);
  } else {
    conv_main<false><<<880, 512, 0, stream>>>(x, w, nullptr, bias, out);
  }
}